// Round 8
// baseline (91.682 us; speedup 1.0000x reference)
//
#include <hip/hip_runtime.h>
#include <hip/hip_fp16.h>

#define SIGMA_C 1e-4f
#define EPS_C   1e-12f
#define WPB     4          // waves per block
#define STEPS   8          // steps per wave; 32 pairs per wave-step

struct V3 { float x, y, z; };

__device__ __forceinline__ V3 v3sub(V3 a, V3 b) { return {a.x - b.x, a.y - b.y, a.z - b.z}; }
__device__ __forceinline__ float v3dot(V3 a, V3 b) { return a.x * b.x + a.y * b.y + a.z * b.z; }
__device__ __forceinline__ V3 v3cross(V3 a, V3 b) {
    return {a.y * b.z - a.z * b.y,
            a.z * b.x - a.x * b.z,
            a.x * b.y - a.y * b.x};
}
__device__ __forceinline__ int imax0(int x) { return x > 0 ? x : 0; }

__device__ __forceinline__ void tri_frame(const V3 v[3], V3& c, V3& n, float& r) {
    const float third = 1.0f / 3.0f;
    c.x = (v[0].x + v[1].x + v[2].x) * third;
    c.y = (v[0].y + v[1].y + v[2].y) * third;
    c.z = (v[0].z + v[1].z + v[2].z) * third;
    V3 e1 = v3sub(v[1], v[0]);
    V3 e2 = v3sub(v[2], v[0]);
    n = v3cross(e1, e2);
    float nn = sqrtf(v3dot(n, n));
    float inv = 1.0f / fmaxf(nn, EPS_C);
    n.x *= inv; n.y *= inv; n.z *= inv;
    V3 d0 = v3sub(v[0], c), d1 = v3sub(v[1], c), d2 = v3sub(v[2], c);
    float m = fmaxf(fmaxf(v3dot(d0, d0), v3dot(d1, d1)), v3dot(d2, d2));
    r = sqrtf(m);
}

__device__ __forceinline__ float cone_psi2(const V3 p[3], V3 c, V3 n, float r) {
    float inv_r = 1.0f / fmaxf(r, EPS_C);
    float s = 0.0f;
#pragma unroll
    for (int i = 0; i < 3; ++i) {
        V3 u = v3sub(p[i], c);
        float h = v3dot(u, n);
        V3 w = {u.x - h * n.x, u.y - h * n.y, u.z - h * n.z};
        float rho = sqrtf(v3dot(w, w));
        float radial = fmaxf(1.0f - rho * inv_r, 0.0f);
        float axial = fmaxf(SIGMA_C - h, 0.0f);   // PENALIZE_OUTSIDE = True
        float psi = radial * axial;
        s += psi * psi;
    }
    return s;
}

// record = 32 B, two 16-B chunks:
// chunkA h[0..7]: v0.x v0.y v0.z v1.x v1.y v1.z v2.x v2.y
// chunkB h[0..7]: c.x  c.y  c.z  n.x  n.y  n.z  r    v2.z
union Chunk { float4 f; __half h[8]; };

// ---------------- phase 1: per-(batch,face) 32-B fp16 record, 2 faces/thread ----------------
__global__ void precompute_tri_h(const float* __restrict__ verts,  // [B,V,3]
                                 const int*   __restrict__ faces,  // [F,3]
                                 float4* __restrict__ table,       // [B*F*2]
                                 float* __restrict__ out,          // [B]
                                 int V, int F, int B) {
    if (blockIdx.x == 0 && threadIdx.x < (unsigned)B)
        out[threadIdx.x] = 0.0f;

    const int b = blockIdx.x % B;      // batch -> XCD co-location with pair kernel
    const int chunk = blockIdx.x / B;
    const int f0 = (chunk * blockDim.x + threadIdx.x) * 2;
    if (f0 >= F) return;
    const int nf = (f0 + 1 < F) ? 2 : 1;

    const float* vb = verts + (size_t)b * (size_t)V * 3u;

    int ia[6];
#pragma unroll
    for (int j = 0; j < 3; ++j) ia[j] = faces[3 * f0 + j];
#pragma unroll
    for (int j = 0; j < 3; ++j) ia[3 + j] = faces[3 * (f0 + nf - 1) + j];

    V3 pv[6];
#pragma unroll
    for (int j = 0; j < 6; ++j) {
        int vi = ia[j];
        pv[j] = {vb[3 * vi + 0], vb[3 * vi + 1], vb[3 * vi + 2]};
    }

#pragma unroll
    for (int k = 0; k < 2; ++k) {
        if (k >= nf) break;
        V3 v[3] = {pv[3 * k], pv[3 * k + 1], pv[3 * k + 2]};
        V3 c, n; float r;
        tri_frame(v, c, n, r);
        Chunk A, Bc;
        A.h[0] = __float2half(v[0].x); A.h[1] = __float2half(v[0].y); A.h[2] = __float2half(v[0].z);
        A.h[3] = __float2half(v[1].x); A.h[4] = __float2half(v[1].y); A.h[5] = __float2half(v[1].z);
        A.h[6] = __float2half(v[2].x); A.h[7] = __float2half(v[2].y);
        Bc.h[0] = __float2half(c.x);   Bc.h[1] = __float2half(c.y);   Bc.h[2] = __float2half(c.z);
        Bc.h[3] = __float2half(n.x);   Bc.h[4] = __float2half(n.y);   Bc.h[5] = __float2half(n.z);
        Bc.h[6] = __float2half(r);     Bc.h[7] = __float2half(v[2].z);
        float4* rec = table + ((size_t)b * F + (f0 + k)) * 2;
        rec[0] = A.f;
        rec[1] = Bc.f;
    }
}

// ---------------- phase 2: lane-pair cooperative gather ----------------
// pair p served by lanes (2k, 2k+1): even computes psi_r (R verts vs I cone),
// odd computes psi_i (I verts vs R cone). Each lane loads chunkA of its
// verts-record and chunkB of its cone-record; the two lanes' loads of each
// record hit the SAME 64-B line -> TA-coalesced (2 lookups/pair, was 4).
__global__ void __launch_bounds__(256)
pair_kernel_coop(const float4* __restrict__ table,  // [B*F*2]
                 const int2*  __restrict__ coll,    // [B*C]
                 float* __restrict__ out,           // [B]
                 int F, int C, int B) {
    const int b = blockIdx.x % B;                  // batch -> XCD pinning
    const int chunk = blockIdx.x / B;
    const int wid  = threadIdx.x >> 6;
    const int lane = threadIdx.x & 63;
    const int half = lane & 1;                     // 0: psi_r lane, 1: psi_i lane
    const int pidx = lane >> 1;

    const int2* cb = coll + (size_t)b * C;
    const char* tb = (const char*)(table + (size_t)b * ((size_t)F * 2));

    const int wave_base = (chunk * WPB + wid) * (32 * STEPS) + pidx;

    // preload pair indices (2 lanes share each int2 -> HW broadcast)
    int2 q[STEPS];
#pragma unroll
    for (int s = 0; s < STEPS; ++s) {
        int pid = wave_base + s * 32;
        q[s] = (pid < C) ? cb[pid] : make_int2(-1, -1);
    }

    // raw load buffers (select deferred to compute so loads stay in flight)
    float4 l0buf[2], l1buf[2];
    {
        const char* Rb = tb + (size_t)imax0(q[0].x) * 32;
        const char* Ib = tb + (size_t)imax0(q[0].y) * 32;
        l0buf[0] = *(const float4*)(Rb + half * 16);        // chunk(half) of R
        l1buf[0] = *(const float4*)(Ib + (half ^ 1) * 16);  // chunk(1-half) of I
    }

    float acc = 0.0f;
#pragma unroll
    for (int s = 0; s < STEPS; ++s) {
        if (s + 1 < STEPS) {
            const char* Rb = tb + (size_t)imax0(q[s + 1].x) * 32;
            const char* Ib = tb + (size_t)imax0(q[s + 1].y) * 32;
            l0buf[(s + 1) & 1] = *(const float4*)(Rb + half * 16);
            l1buf[(s + 1) & 1] = *(const float4*)(Ib + (half ^ 1) * 16);
        }

        // even lane: l0 = chunkA(R) [verts], l1 = chunkB(I) [cone]
        // odd  lane: l0 = chunkB(R) [cone],  l1 = chunkA(I) [verts]
        Chunk A, Bc;
        A.f  = half ? l1buf[s & 1] : l0buf[s & 1];
        Bc.f = half ? l0buf[s & 1] : l1buf[s & 1];

        // my verts-record's v2.z lives in the PARTNER's chunkB dword3 (hi half)
        int send = __float_as_int(Bc.f.w);
        int rcvd = __shfl_xor(send, 1, 64);
        float v2z = __half2float(__ushort_as_half((unsigned short)(((unsigned)rcvd) >> 16)));

        V3 p[3];
        p[0] = {__half2float(A.h[0]), __half2float(A.h[1]), __half2float(A.h[2])};
        p[1] = {__half2float(A.h[3]), __half2float(A.h[4]), __half2float(A.h[5])};
        p[2] = {__half2float(A.h[6]), __half2float(A.h[7]), v2z};
        V3 c = {__half2float(Bc.h[0]), __half2float(Bc.h[1]), __half2float(Bc.h[2])};
        V3 n = {__half2float(Bc.h[3]), __half2float(Bc.h[4]), __half2float(Bc.h[5])};
        float r = __half2float(Bc.h[6]);

        float w = ((q[s].x | q[s].y) >= 0) ? 1.0f : 0.0f;
        acc += w * cone_psi2(p, c, n, r);
    }

    // wave (64) shuffle reduction (covers both halves of every pair)
#pragma unroll
    for (int off = 32; off > 0; off >>= 1)
        acc += __shfl_down(acc, off, 64);

    __shared__ float red[WPB];
    if (lane == 0) red[wid] = acc;
    __syncthreads();
    if (threadIdx.x == 0) {
        float s = 0.0f;
#pragma unroll
        for (int i = 0; i < WPB; ++i) s += red[i];
        atomicAdd(&out[b], s);
    }
}

// ---------------- fallback: direct gather ----------------
__global__ void interp_zero(float* out, int n) {
    int i = blockIdx.x * blockDim.x + threadIdx.x;
    if (i < n) out[i] = 0.0f;
}
__global__ void pair_kernel_gather(const float* __restrict__ verts,
                                   const int*   __restrict__ faces,
                                   const int2*  __restrict__ coll,
                                   float* __restrict__ out, int V, int C) {
    const int b = blockIdx.y;
    const float* vb = verts + (size_t)b * (size_t)V * 3u;
    const int2* cb = coll + (size_t)b * (size_t)C;
    float acc = 0.0f;
    const int stride = gridDim.x * blockDim.x;
    for (int c = blockIdx.x * blockDim.x + threadIdx.x; c < C; c += stride) {
        int2 idx = cb[c];
        if ((idx.x | idx.y) >= 0) {
            const int* fr = faces + 3 * idx.x;
            const int* fi = faces + 3 * idx.y;
            V3 tr[3], ti[3];
#pragma unroll
            for (int j = 0; j < 3; ++j) {
                int vr = fr[j];
                tr[j] = {vb[3 * vr + 0], vb[3 * vr + 1], vb[3 * vr + 2]};
                int vi = fi[j];
                ti[j] = {vb[3 * vi + 0], vb[3 * vi + 1], vb[3 * vi + 2]};
            }
            V3 rc, rn; float rr;
            tri_frame(tr, rc, rn, rr);
            V3 ic, in_; float ir;
            tri_frame(ti, ic, in_, ir);
            acc += cone_psi2(ti, rc, rn, rr);
            acc += cone_psi2(tr, ic, in_, ir);
        }
    }
#pragma unroll
    for (int off = 32; off > 0; off >>= 1)
        acc += __shfl_down(acc, off, 64);
    __shared__ float red[16];
    int lane = threadIdx.x & 63, wid = threadIdx.x >> 6;
    if (lane == 0) red[wid] = acc;
    __syncthreads();
    if (threadIdx.x == 0) {
        float s = 0.0f;
        int nw = blockDim.x >> 6;
        for (int i = 0; i < nw; ++i) s += red[i];
        atomicAdd(&out[b], s);
    }
}

extern "C" void kernel_launch(void* const* d_in, const int* in_sizes, int n_in,
                              void* d_out, int out_size, void* d_ws, size_t ws_size,
                              hipStream_t stream) {
    const float* verts = (const float*)d_in[0];
    const int*   faces = (const int*)d_in[1];
    float* out = (float*)d_out;

    const int B = out_size;                       // 8
    const int V = in_sizes[0] / (3 * B);          // 10475
    const int F = in_sizes[1] / 3;                // 20908
    const int C = in_sizes[2] / (2 * B);          // 262144

    const size_t table_bytes = (size_t)B * (size_t)F * 32u;

    if (ws_size >= table_bytes) {
        float4* table = (float4*)d_ws;

        const int pchunks = (F + 511) / 512;                // 2 faces/thread
        precompute_tri_h<<<dim3(pchunks * B), dim3(256), 0, stream>>>(
            verts, faces, table, out, V, F, B);

        const int pairs_per_block = WPB * 32 * STEPS;       // 1024
        const int bpb = (C + pairs_per_block - 1) / pairs_per_block;  // per batch
        pair_kernel_coop<<<dim3(bpb * B), dim3(WPB * 64), 0, stream>>>(
            table, (const int2*)d_in[2], out, F, C, B);
    } else {
        interp_zero<<<1, 64, 0, stream>>>(out, B);
        pair_kernel_gather<<<dim3(256, B), dim3(256), 0, stream>>>(
            verts, faces, (const int2*)d_in[2], out, V, C);
    }
}

// Round 9
// 67.507 us; speedup vs baseline: 1.3581x; 1.3581x over previous
//
#include <hip/hip_runtime.h>
#include <hip/hip_fp16.h>

#define SIGMA_C 1e-4f
#define EPS_C   1e-12f
#define WPB     4          // waves per block
#define STEPS   4          // pairs per lane-pair per thread

struct V3 { float x, y, z; };

__device__ __forceinline__ V3 v3sub(V3 a, V3 b) { return {a.x - b.x, a.y - b.y, a.z - b.z}; }
__device__ __forceinline__ float v3dot(V3 a, V3 b) { return a.x * b.x + a.y * b.y + a.z * b.z; }
__device__ __forceinline__ V3 v3cross(V3 a, V3 b) {
    return {a.y * b.z - a.z * b.y,
            a.z * b.x - a.x * b.z,
            a.x * b.y - a.y * b.x};
}
__device__ __forceinline__ int imax0(int x) { return x > 0 ? x : 0; }

__device__ __forceinline__ void tri_frame(const V3 v[3], V3& c, V3& n, float& r) {
    const float third = 1.0f / 3.0f;
    c.x = (v[0].x + v[1].x + v[2].x) * third;
    c.y = (v[0].y + v[1].y + v[2].y) * third;
    c.z = (v[0].z + v[1].z + v[2].z) * third;
    V3 e1 = v3sub(v[1], v[0]);
    V3 e2 = v3sub(v[2], v[0]);
    n = v3cross(e1, e2);
    float nn = sqrtf(v3dot(n, n));
    float inv = 1.0f / fmaxf(nn, EPS_C);
    n.x *= inv; n.y *= inv; n.z *= inv;
    V3 d0 = v3sub(v[0], c), d1 = v3sub(v[1], c), d2 = v3sub(v[2], c);
    float m = fmaxf(fmaxf(v3dot(d0, d0), v3dot(d1, d1)), v3dot(d2, d2));
    r = sqrtf(m);
}

__device__ __forceinline__ float cone_psi2(const V3 p[3], V3 c, V3 n, float r) {
    float inv_r = 1.0f / fmaxf(r, EPS_C);
    float s = 0.0f;
#pragma unroll
    for (int i = 0; i < 3; ++i) {
        V3 u = v3sub(p[i], c);
        float h = v3dot(u, n);
        V3 w = {u.x - h * n.x, u.y - h * n.y, u.z - h * n.z};
        float rho = sqrtf(v3dot(w, w));
        float radial = fmaxf(1.0f - rho * inv_r, 0.0f);
        float axial = fmaxf(SIGMA_C - h, 0.0f);   // PENALIZE_OUTSIDE = True
        float psi = radial * axial;
        s += psi * psi;
    }
    return s;
}

// record = 32 B, two 16-B chunks:
// chunkA h[0..7]: v0.x v0.y v0.z v1.x v1.y v1.z v2.x v2.y
// chunkB h[0..7]: c.x  c.y  c.z  n.x  n.y  n.z  r    v2.z
union Chunk { float4 f; __half h[8]; };

// ---------------- phase 1: per-(batch,face) 32-B fp16 record, 2 faces/thread ----------------
__global__ void precompute_tri_h(const float* __restrict__ verts,  // [B,V,3]
                                 const int*   __restrict__ faces,  // [F,3]
                                 float4* __restrict__ table,       // [B*F*2]
                                 float* __restrict__ out,          // [B]
                                 int V, int F, int B) {
    if (blockIdx.x == 0 && threadIdx.x < (unsigned)B)
        out[threadIdx.x] = 0.0f;

    const int b = blockIdx.x % B;      // batch -> XCD co-location with pair kernel
    const int chunk = blockIdx.x / B;
    const int f0 = (chunk * blockDim.x + threadIdx.x) * 2;
    if (f0 >= F) return;
    const int nf = (f0 + 1 < F) ? 2 : 1;

    const float* vb = verts + (size_t)b * (size_t)V * 3u;

    int ia[6];
#pragma unroll
    for (int j = 0; j < 3; ++j) ia[j] = faces[3 * f0 + j];
#pragma unroll
    for (int j = 0; j < 3; ++j) ia[3 + j] = faces[3 * (f0 + nf - 1) + j];

    V3 pv[6];
#pragma unroll
    for (int j = 0; j < 6; ++j) {
        int vi = ia[j];
        pv[j] = {vb[3 * vi + 0], vb[3 * vi + 1], vb[3 * vi + 2]};
    }

#pragma unroll
    for (int k = 0; k < 2; ++k) {
        if (k >= nf) break;
        V3 v[3] = {pv[3 * k], pv[3 * k + 1], pv[3 * k + 2]};
        V3 c, n; float r;
        tri_frame(v, c, n, r);
        Chunk A, Bc;
        A.h[0] = __float2half(v[0].x); A.h[1] = __float2half(v[0].y); A.h[2] = __float2half(v[0].z);
        A.h[3] = __float2half(v[1].x); A.h[4] = __float2half(v[1].y); A.h[5] = __float2half(v[1].z);
        A.h[6] = __float2half(v[2].x); A.h[7] = __float2half(v[2].y);
        Bc.h[0] = __float2half(c.x);   Bc.h[1] = __float2half(c.y);   Bc.h[2] = __float2half(c.z);
        Bc.h[3] = __float2half(n.x);   Bc.h[4] = __float2half(n.y);   Bc.h[5] = __float2half(n.z);
        Bc.h[6] = __float2half(r);     Bc.h[7] = __float2half(v[2].z);
        float4* rec = table + ((size_t)b * F + (f0 + k)) * 2;
        rec[0] = A.f;
        rec[1] = Bc.f;
    }
}

// one half-pair evaluation: lane's verts-chunk vs lane's cone-chunk,
// v2.z recovered from the PARTNER lane's cone-chunk .w (hi half)
__device__ __forceinline__ float compute_half(int2 q, float4 l0, float4 l1, int half) {
    Chunk Vc, Cc;
    Vc.f = half ? l1 : l0;     // verts chunk (A) of my verts-record
    Cc.f = half ? l0 : l1;     // cone chunk (B) of my cone-record
    int rcvd = __shfl_xor(__float_as_int(Cc.f.w), 1, 64);
    float v2z = __half2float(__ushort_as_half((unsigned short)(((unsigned)rcvd) >> 16)));
    V3 p[3];
    p[0] = {__half2float(Vc.h[0]), __half2float(Vc.h[1]), __half2float(Vc.h[2])};
    p[1] = {__half2float(Vc.h[3]), __half2float(Vc.h[4]), __half2float(Vc.h[5])};
    p[2] = {__half2float(Vc.h[6]), __half2float(Vc.h[7]), v2z};
    V3 c = {__half2float(Cc.h[0]), __half2float(Cc.h[1]), __half2float(Cc.h[2])};
    V3 n = {__half2float(Cc.h[3]), __half2float(Cc.h[4]), __half2float(Cc.h[5])};
    float r = __half2float(Cc.h[6]);
    float w = ((q.x | q.y) >= 0) ? 1.0f : 0.0f;
    return w * cone_psi2(p, c, n, r);
}

// ---------------- phase 2: lane-pair coop, hand-unrolled depth-2, named regs ----------------
__global__ void __launch_bounds__(256)
pair_kernel_coop2(const float4* __restrict__ table,  // [B*F*2]
                  const int2*  __restrict__ coll,    // [B*C]
                  float* __restrict__ out,           // [B]
                  int F, int C, int B) {
    const int b = blockIdx.x % B;                  // batch -> XCD pinning
    const int chunk = blockIdx.x / B;
    const int wid  = threadIdx.x >> 6;
    const int lane = threadIdx.x & 63;
    const int half = lane & 1;                     // 0: R-verts/I-cone, 1: I-verts/R-cone
    const int pidx = lane >> 1;

    const int2* cb = coll + (size_t)b * C;
    const char* tb = (const char*)(table + (size_t)b * ((size_t)F * 2));

    const int base = (chunk * WPB + wid) * (32 * STEPS) + pidx;
    const int offV = half * 16;                    // my verts-record chunk offset
    const int offC = (half ^ 1) * 16;              // my cone-record chunk offset

    // 4 pair indices — named scalars, coalesced 8B loads (2 lanes broadcast each)
    int p0 = base, p1 = base + 32, p2 = base + 64, p3 = base + 96;
    int2 q0 = (p0 < C) ? cb[p0] : make_int2(-1, -1);
    int2 q1 = (p1 < C) ? cb[p1] : make_int2(-1, -1);
    int2 q2 = (p2 < C) ? cb[p2] : make_int2(-1, -1);
    int2 q3 = (p3 < C) ? cb[p3] : make_int2(-1, -1);

    // depth-2 pipeline, all-named buffers (round-4-proven structure)
    float4 a0 = *(const float4*)(tb + (size_t)imax0(q0.x) * 32 + offV);
    float4 a1 = *(const float4*)(tb + (size_t)imax0(q0.y) * 32 + offC);
    float4 b0 = *(const float4*)(tb + (size_t)imax0(q1.x) * 32 + offV);
    float4 b1 = *(const float4*)(tb + (size_t)imax0(q1.y) * 32 + offC);

    float acc = compute_half(q0, a0, a1, half);

    float4 c0 = *(const float4*)(tb + (size_t)imax0(q2.x) * 32 + offV);
    float4 c1 = *(const float4*)(tb + (size_t)imax0(q2.y) * 32 + offC);
    acc += compute_half(q1, b0, b1, half);

    float4 d0 = *(const float4*)(tb + (size_t)imax0(q3.x) * 32 + offV);
    float4 d1 = *(const float4*)(tb + (size_t)imax0(q3.y) * 32 + offC);
    acc += compute_half(q2, c0, c1, half);
    acc += compute_half(q3, d0, d1, half);

    // wave (64) shuffle reduction (covers both halves of every pair)
#pragma unroll
    for (int off = 32; off > 0; off >>= 1)
        acc += __shfl_down(acc, off, 64);

    __shared__ float red[WPB];
    if (lane == 0) red[wid] = acc;
    __syncthreads();
    if (threadIdx.x == 0) {
        float s = 0.0f;
#pragma unroll
        for (int i = 0; i < WPB; ++i) s += red[i];
        atomicAdd(&out[b], s);
    }
}

// ---------------- fallback: direct gather ----------------
__global__ void interp_zero(float* out, int n) {
    int i = blockIdx.x * blockDim.x + threadIdx.x;
    if (i < n) out[i] = 0.0f;
}
__global__ void pair_kernel_gather(const float* __restrict__ verts,
                                   const int*   __restrict__ faces,
                                   const int2*  __restrict__ coll,
                                   float* __restrict__ out, int V, int C) {
    const int b = blockIdx.y;
    const float* vb = verts + (size_t)b * (size_t)V * 3u;
    const int2* cb = coll + (size_t)b * (size_t)C;
    float acc = 0.0f;
    const int stride = gridDim.x * blockDim.x;
    for (int c = blockIdx.x * blockDim.x + threadIdx.x; c < C; c += stride) {
        int2 idx = cb[c];
        if ((idx.x | idx.y) >= 0) {
            const int* fr = faces + 3 * idx.x;
            const int* fi = faces + 3 * idx.y;
            V3 tr[3], ti[3];
#pragma unroll
            for (int j = 0; j < 3; ++j) {
                int vr = fr[j];
                tr[j] = {vb[3 * vr + 0], vb[3 * vr + 1], vb[3 * vr + 2]};
                int vi = fi[j];
                ti[j] = {vb[3 * vi + 0], vb[3 * vi + 1], vb[3 * vi + 2]};
            }
            V3 rc, rn; float rr;
            tri_frame(tr, rc, rn, rr);
            V3 ic, in_; float ir;
            tri_frame(ti, ic, in_, ir);
            acc += cone_psi2(ti, rc, rn, rr);
            acc += cone_psi2(tr, ic, in_, ir);
        }
    }
#pragma unroll
    for (int off = 32; off > 0; off >>= 1)
        acc += __shfl_down(acc, off, 64);
    __shared__ float red[16];
    int lane = threadIdx.x & 63, wid = threadIdx.x >> 6;
    if (lane == 0) red[wid] = acc;
    __syncthreads();
    if (threadIdx.x == 0) {
        float s = 0.0f;
        int nw = blockDim.x >> 6;
        for (int i = 0; i < nw; ++i) s += red[i];
        atomicAdd(&out[b], s);
    }
}

extern "C" void kernel_launch(void* const* d_in, const int* in_sizes, int n_in,
                              void* d_out, int out_size, void* d_ws, size_t ws_size,
                              hipStream_t stream) {
    const float* verts = (const float*)d_in[0];
    const int*   faces = (const int*)d_in[1];
    float* out = (float*)d_out;

    const int B = out_size;                       // 8
    const int V = in_sizes[0] / (3 * B);          // 10475
    const int F = in_sizes[1] / 3;                // 20908
    const int C = in_sizes[2] / (2 * B);          // 262144

    const size_t table_bytes = (size_t)B * (size_t)F * 32u;

    if (ws_size >= table_bytes) {
        float4* table = (float4*)d_ws;

        const int pchunks = (F + 511) / 512;                // 2 faces/thread
        precompute_tri_h<<<dim3(pchunks * B), dim3(256), 0, stream>>>(
            verts, faces, table, out, V, F, B);

        const int pairs_per_block = WPB * 32 * STEPS;       // 512
        const int bpb = (C + pairs_per_block - 1) / pairs_per_block;  // per batch: 512
        pair_kernel_coop2<<<dim3(bpb * B), dim3(WPB * 64), 0, stream>>>(
            table, (const int2*)d_in[2], out, F, C, B);
    } else {
        interp_zero<<<1, 64, 0, stream>>>(out, B);
        pair_kernel_gather<<<dim3(256, B), dim3(256), 0, stream>>>(
            verts, faces, (const int2*)d_in[2], out, V, C);
    }
}

// Round 10
// 30.605 us; speedup vs baseline: 2.9957x; 2.2058x over previous
//
#include <hip/hip_runtime.h>

#define SIGMA_C 1e-4f
#define EPS_C   1e-12f
#define GPT     4          // int4 groups per thread, 2 pairs per group -> 8 pairs/thread

struct V3 { float x, y, z; };
typedef float v2f __attribute__((ext_vector_type(2)));

__device__ __forceinline__ V3 v3sub(V3 a, V3 b) { return {a.x - b.x, a.y - b.y, a.z - b.z}; }
__device__ __forceinline__ float v3dot(V3 a, V3 b) { return a.x * b.x + a.y * b.y + a.z * b.z; }
__device__ __forceinline__ V3 v3cross(V3 a, V3 b) {
    return {a.y * b.z - a.z * b.y,
            a.z * b.x - a.x * b.z,
            a.x * b.y - a.y * b.x};
}
__device__ __forceinline__ int imax0(int x) { return x > 0 ? x : 0; }

__device__ __forceinline__ void tri_frame(const V3 v[3], V3& c, V3& n, float& r) {
    const float third = 1.0f / 3.0f;
    c.x = (v[0].x + v[1].x + v[2].x) * third;
    c.y = (v[0].y + v[1].y + v[2].y) * third;
    c.z = (v[0].z + v[1].z + v[2].z) * third;
    V3 e1 = v3sub(v[1], v[0]);
    V3 e2 = v3sub(v[2], v[0]);
    n = v3cross(e1, e2);
    float nn = sqrtf(v3dot(n, n));
    float inv = 1.0f / fmaxf(nn, EPS_C);
    n.x *= inv; n.y *= inv; n.z *= inv;
    V3 d0 = v3sub(v[0], c), d1 = v3sub(v[1], c), d2 = v3sub(v[2], c);
    float m = fmaxf(fmaxf(v3dot(d0, d0), v3dot(d1, d1)), v3dot(d2, d2));
    r = sqrtf(m);
}

__device__ __forceinline__ float cone_psi2(const V3 p[3], V3 c, V3 n, float r) {
    float inv_r = 1.0f / fmaxf(r, EPS_C);
    float s = 0.0f;
#pragma unroll
    for (int i = 0; i < 3; ++i) {
        V3 u = v3sub(p[i], c);
        float h = v3dot(u, n);
        V3 w = {u.x - h * n.x, u.y - h * n.y, u.z - h * n.z};
        float rho = sqrtf(v3dot(w, w));
        float radial = fmaxf(1.0f - rho * inv_r, 0.0f);
        float axial = fmaxf(SIGMA_C - h, 0.0f);   // PENALIZE_OUTSIDE = True
        float psi = radial * axial;
        s += psi * psi;
    }
    return s;
}

// fp8 e4m3 record: 16 bytes, one dwordx4 load.
// b0..b8 = v0 v1 v2 (xyz each), b9..b11 = c, b12..b14 = n, b15 = r
struct RecF { V3 p0, p1, p2, c, n; float r; };

__device__ __forceinline__ void decode_rec8(float4 q, RecF& o) {
    int4 d = *(int4*)&q;
    v2f t0 = __builtin_amdgcn_cvt_pk_f32_fp8(d.x, false);  // v0.x v0.y
    v2f t1 = __builtin_amdgcn_cvt_pk_f32_fp8(d.x, true);   // v0.z v1.x
    v2f t2 = __builtin_amdgcn_cvt_pk_f32_fp8(d.y, false);  // v1.y v1.z
    v2f t3 = __builtin_amdgcn_cvt_pk_f32_fp8(d.y, true);   // v2.x v2.y
    v2f t4 = __builtin_amdgcn_cvt_pk_f32_fp8(d.z, false);  // v2.z c.x
    v2f t5 = __builtin_amdgcn_cvt_pk_f32_fp8(d.z, true);   // c.y  c.z
    v2f t6 = __builtin_amdgcn_cvt_pk_f32_fp8(d.w, false);  // n.x  n.y
    v2f t7 = __builtin_amdgcn_cvt_pk_f32_fp8(d.w, true);   // n.z  r
    o.p0 = {t0.x, t0.y, t1.x};
    o.p1 = {t1.y, t2.x, t2.y};
    o.p2 = {t3.x, t3.y, t4.x};
    o.c  = {t4.y, t5.x, t5.y};
    o.n  = {t6.x, t6.y, t7.x};
    o.r  = t7.y;
}

__device__ __forceinline__ float compute_pair8(float4 R, float4 I, float w) {
    RecF rr, ii;
    decode_rec8(R, rr);
    decode_rec8(I, ii);
    V3 rp[3] = {rr.p0, rr.p1, rr.p2};
    V3 ip[3] = {ii.p0, ii.p1, ii.p2};
    return w * (cone_psi2(ip, rr.c, rr.n, rr.r) + cone_psi2(rp, ii.c, ii.n, ii.r));
}

// ---------------- phase 1: per-(batch,face) 16-B fp8 record, 2 faces/thread ----------------
__global__ void precompute_tri_8(const float* __restrict__ verts,  // [B,V,3]
                                 const int*   __restrict__ faces,  // [F,3]
                                 float4* __restrict__ table,       // [B*F]
                                 float* __restrict__ out,          // [B]
                                 int V, int F, int B) {
    if (blockIdx.x == 0 && threadIdx.x < (unsigned)B)
        out[threadIdx.x] = 0.0f;

    const int b = blockIdx.x % B;      // batch -> XCD co-location with pair kernel
    const int chunk = blockIdx.x / B;
    const int f0 = (chunk * blockDim.x + threadIdx.x) * 2;
    if (f0 >= F) return;
    const int nf = (f0 + 1 < F) ? 2 : 1;

    const float* vb = verts + (size_t)b * (size_t)V * 3u;

    int ia[6];
#pragma unroll
    for (int j = 0; j < 3; ++j) ia[j] = faces[3 * f0 + j];
#pragma unroll
    for (int j = 0; j < 3; ++j) ia[3 + j] = faces[3 * (f0 + nf - 1) + j];

    V3 pv[6];
#pragma unroll
    for (int j = 0; j < 6; ++j) {
        int vi = ia[j];
        pv[j] = {vb[3 * vi + 0], vb[3 * vi + 1], vb[3 * vi + 2]};
    }

#pragma unroll
    for (int k = 0; k < 2; ++k) {
        if (k >= nf) break;
        V3 v[3] = {pv[3 * k], pv[3 * k + 1], pv[3 * k + 2]};
        V3 c, n; float r;
        tri_frame(v, c, n, r);
        int d0 = 0, d1 = 0, d2 = 0, d3 = 0;
        d0 = __builtin_amdgcn_cvt_pk_fp8_f32(v[0].x, v[0].y, d0, false);
        d0 = __builtin_amdgcn_cvt_pk_fp8_f32(v[0].z, v[1].x, d0, true);
        d1 = __builtin_amdgcn_cvt_pk_fp8_f32(v[1].y, v[1].z, d1, false);
        d1 = __builtin_amdgcn_cvt_pk_fp8_f32(v[2].x, v[2].y, d1, true);
        d2 = __builtin_amdgcn_cvt_pk_fp8_f32(v[2].z, c.x, d2, false);
        d2 = __builtin_amdgcn_cvt_pk_fp8_f32(c.y, c.z, d2, true);
        d3 = __builtin_amdgcn_cvt_pk_fp8_f32(n.x, n.y, d3, false);
        d3 = __builtin_amdgcn_cvt_pk_fp8_f32(n.z, r, d3, true);
        int4 rec = {d0, d1, d2, d3};
        table[(size_t)b * F + (f0 + k)] = *(float4*)&rec;
    }
}

// ---------------- phase 2: R4-proven ping-pong, fp8 records (2 gathers/pair) ----------------
__device__ __forceinline__ void gather_group8(const float4* __restrict__ tb, int4 q,
                                              float4 G[4], float w[2]) {
    w[0] = ((q.x | q.y) >= 0) ? 1.0f : 0.0f;
    w[1] = ((q.z | q.w) >= 0) ? 1.0f : 0.0f;
    G[0] = tb[imax0(q.x)];
    G[1] = tb[imax0(q.y)];
    G[2] = tb[imax0(q.z)];
    G[3] = tb[imax0(q.w)];
}
__device__ __forceinline__ float compute_group8(const float4 G[4], const float w[2]) {
    return compute_pair8(G[0], G[1], w[0]) + compute_pair8(G[2], G[3], w[1]);
}

__global__ void __launch_bounds__(256)
pair_kernel_f8(const float4* __restrict__ table,  // [B*F]
               const int4*  __restrict__ coll4,   // [B*C4]
               float* __restrict__ out,           // [B]
               int F, int C4, int B) {
    const int b = blockIdx.x % B;                 // batch -> XCD pinning
    const int chunk = blockIdx.x / B;
    const int4* cb = coll4 + (size_t)b * C4;
    const float4* tb = table + (size_t)b * (size_t)F;
    const int base = chunk * (256 * GPT) + threadIdx.x;

    float acc = 0.0f;
    float4 GA[4], GB[4];
    float wA[2], wB[2];
    int4 q_even, q_odd;
    {
        int g0 = base, g1 = base + 256;
        q_even = (g0 < C4) ? cb[g0] : make_int4(-1, -1, -1, -1);
        q_odd  = (g1 < C4) ? cb[g1] : make_int4(-1, -1, -1, -1);
        gather_group8(tb, q_even, GA, wA);
    }
#pragma unroll
    for (int i = 0; i < GPT; ++i) {
        if ((i & 1) == 0) {
            if (i + 2 < GPT) {
                int g = base + (i + 2) * 256;
                q_even = (g < C4) ? cb[g] : make_int4(-1, -1, -1, -1);
            }
            if (i + 1 < GPT) gather_group8(tb, q_odd, GB, wB);
            acc += compute_group8(GA, wA);
        } else {
            if (i + 2 < GPT) {
                int g = base + (i + 2) * 256;
                q_odd = (g < C4) ? cb[g] : make_int4(-1, -1, -1, -1);
            }
            if (i + 1 < GPT) gather_group8(tb, q_even, GA, wA);
            acc += compute_group8(GB, wB);
        }
    }

    // wave (64) shuffle reduction
#pragma unroll
    for (int off = 32; off > 0; off >>= 1)
        acc += __shfl_down(acc, off, 64);

    __shared__ float red[4];
    int lane = threadIdx.x & 63;
    int wid  = threadIdx.x >> 6;
    if (lane == 0) red[wid] = acc;
    __syncthreads();
    if (threadIdx.x == 0) {
        float s = red[0] + red[1] + red[2] + red[3];
        atomicAdd(&out[b], s);
    }
}

// ---------------- fallback: direct gather (fp32 exact) ----------------
__global__ void interp_zero(float* out, int n) {
    int i = blockIdx.x * blockDim.x + threadIdx.x;
    if (i < n) out[i] = 0.0f;
}
__global__ void pair_kernel_gather(const float* __restrict__ verts,
                                   const int*   __restrict__ faces,
                                   const int2*  __restrict__ coll,
                                   float* __restrict__ out, int V, int C) {
    const int b = blockIdx.y;
    const float* vb = verts + (size_t)b * (size_t)V * 3u;
    const int2* cb = coll + (size_t)b * (size_t)C;
    float acc = 0.0f;
    const int stride = gridDim.x * blockDim.x;
    for (int c = blockIdx.x * blockDim.x + threadIdx.x; c < C; c += stride) {
        int2 idx = cb[c];
        if ((idx.x | idx.y) >= 0) {
            const int* fr = faces + 3 * idx.x;
            const int* fi = faces + 3 * idx.y;
            V3 tr[3], ti[3];
#pragma unroll
            for (int j = 0; j < 3; ++j) {
                int vr = fr[j];
                tr[j] = {vb[3 * vr + 0], vb[3 * vr + 1], vb[3 * vr + 2]};
                int vi = fi[j];
                ti[j] = {vb[3 * vi + 0], vb[3 * vi + 1], vb[3 * vi + 2]};
            }
            V3 rc, rn; float rr;
            tri_frame(tr, rc, rn, rr);
            V3 ic, in_; float ir;
            tri_frame(ti, ic, in_, ir);
            acc += cone_psi2(ti, rc, rn, rr);
            acc += cone_psi2(tr, ic, in_, ir);
        }
    }
#pragma unroll
    for (int off = 32; off > 0; off >>= 1)
        acc += __shfl_down(acc, off, 64);
    __shared__ float red[16];
    int lane = threadIdx.x & 63, wid = threadIdx.x >> 6;
    if (lane == 0) red[wid] = acc;
    __syncthreads();
    if (threadIdx.x == 0) {
        float s = 0.0f;
        int nw = blockDim.x >> 6;
        for (int i = 0; i < nw; ++i) s += red[i];
        atomicAdd(&out[b], s);
    }
}

extern "C" void kernel_launch(void* const* d_in, const int* in_sizes, int n_in,
                              void* d_out, int out_size, void* d_ws, size_t ws_size,
                              hipStream_t stream) {
    const float* verts = (const float*)d_in[0];
    const int*   faces = (const int*)d_in[1];
    float* out = (float*)d_out;

    const int B = out_size;                       // 8
    const int V = in_sizes[0] / (3 * B);          // 10475
    const int F = in_sizes[1] / 3;                // 20908
    const int C = in_sizes[2] / (2 * B);          // 262144

    const size_t table_bytes = (size_t)B * (size_t)F * 16u;

    if (ws_size >= table_bytes && (C % 2) == 0) {
        float4* table = (float4*)d_ws;

        const int pchunks = (F + 511) / 512;                // 2 faces/thread
        precompute_tri_8<<<dim3(pchunks * B), dim3(256), 0, stream>>>(
            verts, faces, table, out, V, F, B);

        const int C4 = C / 2;                               // int4 groups per batch
        const int per_block = 256 * GPT;                    // int4 groups per block
        const int chunks = (C4 + per_block - 1) / per_block;
        pair_kernel_f8<<<dim3(chunks * B), dim3(256), 0, stream>>>(
            table, (const int4*)d_in[2], out, F, C4, B);
    } else {
        interp_zero<<<1, 64, 0, stream>>>(out, B);
        pair_kernel_gather<<<dim3(256, B), dim3(256), 0, stream>>>(
            verts, faces, (const int2*)d_in[2], out, V, C);
    }
}